// Round 10
// baseline (444.633 us; speedup 1.0000x reference)
//
#include <hip/hip_runtime.h>
#include <math.h>

#define PI_F 3.14159265358979323846f

// broadcast lane l's value of v to all lanes (v_readlane -> SGPR)
__device__ __forceinline__ float lane_bcast(float v, int l) {
  return __int_as_float(__builtin_amdgcn_readlane(__float_as_int(v), l));
}

// ---------------- wave reduce ----------------
__device__ __forceinline__ float wave_reduce_sum(float v) {
  v += __shfl_xor(v, 32, 64);
  v += __shfl_xor(v, 16, 64);
  v += __shfl_xor(v, 8, 64);
  v += __shfl_xor(v, 4, 64);
  v += __shfl_xor(v, 2, 64);
  v += __shfl_xor(v, 1, 64);
  return v;
}

// ---------------- LayerNorm: one 64-lane wave per token (C=192) ----------------
__global__ __launch_bounds__(64) void ln_kernel(const float* __restrict__ x,
    const float* __restrict__ w, const float* __restrict__ b, float* __restrict__ o) {
  int row = blockIdx.x;
  int lane = threadIdx.x;
  const float* xr = x + row * 192;
  float v0 = xr[lane], v1 = xr[lane + 64], v2 = xr[lane + 128];
  float s  = wave_reduce_sum(v0 + v1 + v2);
  float s2 = wave_reduce_sum(v0 * v0 + v1 * v1 + v2 * v2);
  float mu  = s * (1.f / 192.f);
  float var = s2 * (1.f / 192.f) - mu * mu;
  float rs  = rsqrtf(var + 1e-5f);
  float* orow = o + row * 192;
  orow[lane]       = (v0 - mu) * rs * w[lane]       + b[lane];
  orow[lane + 64]  = (v1 - mu) * rs * w[lane + 64]  + b[lane + 64];
  orow[lane + 128] = (v2 - mu) * rs * w[lane + 128] + b[lane + 128];
}

// ---------------- pipelined tiled GEMM 64x64: C = A @ W^T (+res) ----------------
__global__ __launch_bounds__(256) void gemm_tn(const float* __restrict__ A,
    const float* __restrict__ W, const float* __restrict__ res, float* __restrict__ C,
    int M, int N, int K) {
  __shared__ float As[2][32][68];   // [buf][k][m]
  __shared__ float Ws[2][32][68];   // [buf][k][n]
  int tid = threadIdx.x;
  int m0 = blockIdx.y * 64, n0 = blockIdx.x * 64;
  int tr = tid >> 4, tc = tid & 15;
  int sm  = tid >> 3;
  int skq = tid & 7;
  float4 aP[2], wP[2];
#pragma unroll
  for (int j = 0; j < 2; ++j) {
    int m = sm + j * 32;
    aP[j] = *(const float4*)(A + (size_t)(m0 + m) * K + skq * 4);
    int n = n0 + m;
    if (n < N) wP[j] = *(const float4*)(W + (size_t)n * K + skq * 4);
    else       wP[j] = make_float4(0.f, 0.f, 0.f, 0.f);
  }
#pragma unroll
  for (int j = 0; j < 2; ++j) {
    int m = sm + j * 32;
    As[0][skq * 4 + 0][m] = aP[j].x;
    As[0][skq * 4 + 1][m] = aP[j].y;
    As[0][skq * 4 + 2][m] = aP[j].z;
    As[0][skq * 4 + 3][m] = aP[j].w;
    Ws[0][skq * 4 + 0][m] = wP[j].x;
    Ws[0][skq * 4 + 1][m] = wP[j].y;
    Ws[0][skq * 4 + 2][m] = wP[j].z;
    Ws[0][skq * 4 + 3][m] = wP[j].w;
  }
  __syncthreads();
  float acc[4][4] = {{0.f}};
  int nk = K >> 5;
  for (int it = 0; it < nk; ++it) {
    int cur = it & 1, nxt = cur ^ 1;
    if (it + 1 < nk) {
      int kk = (it + 1) << 5;
#pragma unroll
      for (int j = 0; j < 2; ++j) {
        int m = sm + j * 32;
        aP[j] = *(const float4*)(A + (size_t)(m0 + m) * K + kk + skq * 4);
        int n = n0 + m;
        if (n < N) wP[j] = *(const float4*)(W + (size_t)n * K + kk + skq * 4);
        else       wP[j] = make_float4(0.f, 0.f, 0.f, 0.f);
      }
    }
#pragma unroll
    for (int k = 0; k < 32; ++k) {
      float4 a4 = *(const float4*)&As[cur][k][tr * 4];
      float4 w4 = *(const float4*)&Ws[cur][k][tc * 4];
      float a[4] = {a4.x, a4.y, a4.z, a4.w};
      float bb[4] = {w4.x, w4.y, w4.z, w4.w};
#pragma unroll
      for (int i = 0; i < 4; ++i)
#pragma unroll
        for (int j = 0; j < 4; ++j)
          acc[i][j] = fmaf(a[i], bb[j], acc[i][j]);
    }
    if (it + 1 < nk) {
#pragma unroll
      for (int j = 0; j < 2; ++j) {
        int m = sm + j * 32;
        As[nxt][skq * 4 + 0][m] = aP[j].x;
        As[nxt][skq * 4 + 1][m] = aP[j].y;
        As[nxt][skq * 4 + 2][m] = aP[j].z;
        As[nxt][skq * 4 + 3][m] = aP[j].w;
        Ws[nxt][skq * 4 + 0][m] = wP[j].x;
        Ws[nxt][skq * 4 + 1][m] = wP[j].y;
        Ws[nxt][skq * 4 + 2][m] = wP[j].z;
        Ws[nxt][skq * 4 + 3][m] = wP[j].w;
      }
      __syncthreads();
    }
  }
#pragma unroll
  for (int i = 0; i < 4; ++i) {
    int m = m0 + tr * 4 + i;
#pragma unroll
    for (int j = 0; j < 4; ++j) {
      int n = n0 + tc * 4 + j;
      if (n < N) {
        float v = acc[i][j];
        if (res) v += res[m * N + n];
        C[m * N + n] = v;
      }
    }
  }
}

// ---------------- causal depthwise conv1d(k=4) + SiLU ----------------
__global__ __launch_bounds__(256) void conv_silu(const float* __restrict__ xz,
    const float* __restrict__ cw, const float* __restrict__ cb, float* __restrict__ xc) {
  int e = blockIdx.x * 256 + threadIdx.x;
  if (e >= 4 * 1024 * 384) return;
  int d = e % 384;
  int t = (e / 384) % 1024;
  int b = e / (384 * 1024);
  const float* base = xz + (size_t)(b * 1024) * 768 + d;
  float acc = cb[d];
#pragma unroll
  for (int j = 0; j < 4; ++j) {
    int tt = t - 3 + j;
    if (tt >= 0) acc += base[(size_t)tt * 768] * cw[d * 4 + j];
  }
  float sg = 1.f / (1.f + __expf(-acc));
  xc[e] = acc * sg;
}

// ---------------- delta + transpose: dltT[b,d,t], duT[b,d,t] = dlt*xc ------
__global__ __launch_bounds__(256) void delta_trans(const float* __restrict__ dbc,
    const float* __restrict__ dtw, const float* __restrict__ dtb,
    const float* __restrict__ xc, float* __restrict__ dltT, float* __restrict__ duT) {
  __shared__ float dts[64][13];
  __shared__ float xt[64][65];
  int blk = blockIdx.x;           // 4 * 16 * 6 = 384
  int b  = blk / 96;
  int rem = blk % 96;
  int tt = rem / 6, dd = rem % 6;
  int t0 = tt * 64, d0 = dd * 64;
  int tid = threadIdx.x;
  for (int i = tid; i < 64 * 12; i += 256) {
    int tl = i / 12, r = i % 12;
    dts[tl][r] = dbc[((size_t)b * 1024 + t0 + tl) * 140 + r];
  }
  {
    int col = tid & 63, rg = tid >> 6;
#pragma unroll
    for (int j = 0; j < 16; ++j) {
      int row = j * 4 + rg;
      xt[row][col] = xc[((size_t)b * 1024 + t0 + row) * 384 + d0 + col];
    }
  }
  __syncthreads();
  int tl = tid & 63, grp = tid >> 6;
#pragma unroll
  for (int j = 0; j < 16; ++j) {
    int dl = grp * 16 + j;
    int d = d0 + dl;
    float s = dtb[d];
#pragma unroll
    for (int r = 0; r < 12; ++r) s += dts[tl][r] * dtw[d * 12 + r];
    float dlt = (s > 20.f) ? s : log1pf(__expf(s));
    size_t ob = ((size_t)b * 384 + d) * 1024 + t0 + tl;
    dltT[ob] = dlt;
    duT[ob]  = dlt * xt[tl][dl];
  }
}

// ---------------- FUSED selective scan: p1+p2+p3+gate, one block per (b,d) ----
// 512 threads = 8 waves = 8 chunks of 128 steps. Chunk dv/du loaded ONCE into
// registers (reused across phases). Chunk decay P = exp2(A*sum(dv)) -- exp of
// sum replaces 128 serial multiplies. All strided streams addressed as
// block-uniform base + 32-bit int element offsets (saddr-form loads).
__global__ __launch_bounds__(512) void scan_fused(const float* __restrict__ dltT,
    const float* __restrict__ duT, const float* __restrict__ dbc,
    const float* __restrict__ A_log, const float* __restrict__ xc,
    const float* __restrict__ xz, const float* __restrict__ Dvec,
    float* __restrict__ y) {
  __shared__ float tile[8][16][65];
  __shared__ float psP[8][64];
  __shared__ float psS[8][64];
  int bd = blockIdx.x;
  int b = bd / 384, d = bd % 384;
  int tid = threadIdx.x;
  int c = tid >> 6;        // wave index = chunk
  int lane = tid & 63;
  float A = -__expf(A_log[d * 64 + lane]) * 1.44269504f;
  int t0 = c * 128;
  const float* dT   = dltT + ((size_t)b * 384 + d) * 1024 + t0;
  const float* uT   = duT  + ((size_t)b * 384 + d) * 1024 + t0;
  const float* dbcB = dbc  + ((size_t)b * 1024 + t0) * 140;   // uniform base
  // chunk dv/du: load once, reuse in both phases
  float dv0 = dT[lane],      du0 = uT[lane];
  float dv1 = dT[64 + lane], du1 = uT[64 + lane];
  // P = exp2(A * sum dv)  (product of per-step decays)
  float Pv = exp2f(A * wave_reduce_sum(dv0 + dv1));
  // ---- phase 1: chunk S ----
  float Sv = 0.f;
#pragma unroll
  for (int half = 0; half < 2; ++half) {
    float dv64 = half ? dv1 : dv0;
    float du64 = half ? du1 : du0;
#pragma unroll
    for (int tb = 0; tb < 64; tb += 16) {
      int ts = half * 64 + tb;
      float Bv[16];
#pragma unroll
      for (int i = 0; i < 16; ++i)
        Bv[i] = dbcB[12 + lane + (ts + i) * 140];
#pragma unroll
      for (int i = 0; i < 16; ++i) {
        float sdv = lane_bcast(dv64, tb + i);
        float sdu = lane_bcast(du64, tb + i);
        float a = exp2f(sdv * A);
        Sv = fmaf(Sv, a, sdu * Bv[i]);
      }
    }
  }
  psP[c][lane] = Pv;
  psS[c][lane] = Sv;
  __syncthreads();
  // ---- combine: h_init for this wave's chunk ----
  float h = 0.f;
  for (int k = 0; k < c; ++k)
    h = fmaf(psP[k][lane], h, psS[k][lane]);
  // ---- phase 2: replay + gated write ----
  float ddv = Dvec[d];
  float* yp        = y  + ((size_t)b * 1024 + t0) * 384 + d;
  const float* xcp = xc + ((size_t)b * 1024 + t0) * 384 + d;
  const float* xzp = xz + ((size_t)b * 1024 + t0) * 768 + 384 + d;
  int tq = lane & 15;
  int q  = lane >> 4;
#pragma unroll
  for (int half = 0; half < 2; ++half) {
    float dv64 = half ? dv1 : dv0;
    float du64 = half ? du1 : du0;
#pragma unroll
    for (int tb = 0; tb < 64; tb += 16) {
      int ts = half * 64 + tb;
      float Bv[16], Cv[16];
#pragma unroll
      for (int i = 0; i < 16; ++i) {
        int ro = 12 + lane + (ts + i) * 140;
        Bv[i] = dbcB[ro];
        Cv[i] = dbcB[ro + 64];
      }
      float xcv = 0.f, zv = 0.f;
      if (lane < 16) {
        xcv = xcp[(ts + lane) * 384];
        zv  = xzp[(ts + lane) * 768];
      }
#pragma unroll
      for (int i = 0; i < 16; ++i) {
        float sdv = lane_bcast(dv64, tb + i);
        float sdu = lane_bcast(du64, tb + i);
        float a = exp2f(sdv * A);
        h = fmaf(h, a, sdu * Bv[i]);
        tile[c][i][lane] = h * Cv[i];
      }
      const float* trow = &tile[c][tq][q * 16];
      float s = 0.f;
#pragma unroll
      for (int i = 0; i < 16; ++i) s += trow[i];
      s += __shfl_xor(s, 16, 64);
      s += __shfl_xor(s, 32, 64);
      if (lane < 16) {
        float sg = zv / (1.f + __expf(-zv));
        yp[(ts + lane) * 384] = (s + xcv * ddv) * sg;
      }
    }
  }
}

// ---------------- 1024-pt radix-2 FFT in LDS with twiddle table ----------------
__device__ __forceinline__ void fft1024t(float* __restrict__ re,
    float* __restrict__ im, const float* __restrict__ twc,
    const float* __restrict__ tws, int tid) {
  for (int i = tid; i < 1024; i += 256) {
    int r = (int)(__brev((unsigned)i) >> 22);
    if (i < r) {
      float tr = re[i]; re[i] = re[r]; re[r] = tr;
      float ti = im[i]; im[i] = im[r]; im[r] = ti;
    }
  }
  __syncthreads();
  for (int s = 0; s < 10; ++s) {
    int half = 1 << s;
    int shift = 9 - s;
#pragma unroll
    for (int uu = 0; uu < 2; ++uu) {
      int u = tid + uu * 256;
      int j = u & (half - 1);
      int i0 = ((u >> s) << (s + 1)) + j;
      int i1 = i0 + half;
      int idx = j << shift;
      float cw = twc[idx];
      float sw = tws[idx];
      float br = re[i1], bi = im[i1];
      float tr = br * cw - bi * sw;
      float ti = br * sw + bi * cw;
      float ar = re[i0], ai = im[i0];
      re[i1] = ar - tr; im[i1] = ai - ti;
      re[i0] = ar + tr; im[i0] = ai + ti;
    }
    __syncthreads();
  }
}

// forward fft2: one block per (Bi,d,c). Inline 4-pt DFT over c on load.
__global__ __launch_bounds__(256) void fft_fwd(const float* __restrict__ xin,
    float* __restrict__ Xre, float* __restrict__ Xim) {
  __shared__ float re[1024];
  __shared__ float im[1024];
  __shared__ float twc[512];
  __shared__ float tws[512];
  int blk = blockIdx.x;
  int c = blk & 3;
  int rest = blk >> 2;
  int d = rest % 48, Bi = rest / 48;
  int tid = threadIdx.x;
  for (int k = tid; k < 512; k += 256) {
    float sv, cv;
    __sincosf(-PI_F * (float)k * (1.f / 512.f), &sv, &cv);
    twc[k] = cv; tws[k] = sv;
  }
  for (int n = tid; n < 1024; n += 256) {
    const float* p = xin + (size_t)(Bi * 1024 + n) * 192 + d;
    float v0 = p[0], v1 = p[48], v2 = p[96], v3 = p[144];
    float rr, ii;
    if (c == 0)      { rr = v0 + v1 + v2 + v3; ii = 0.f; }
    else if (c == 1) { rr = v0 - v2;           ii = -(v1 - v3); }
    else if (c == 2) { rr = v0 - v1 + v2 - v3; ii = 0.f; }
    else             { rr = v0 - v2;           ii = (v1 - v3); }
    re[n] = rr; im[n] = ii;
  }
  __syncthreads();
  fft1024t(re, im, twc, tws, tid);
  for (int k = tid; k < 1024; k += 256) {
    size_t o = ((size_t)(Bi * 1024 + k) * 4 + c) * 48 + d;
    Xre[o] = re[k] * (1.f / 64.f);
    Xim[o] = im[k] * (1.f / 64.f);
  }
}

// ---------------- EinFFT frequency mix, layer 1 ----------------
__global__ __launch_bounds__(256) void mix_l1(const float* __restrict__ Xre,
    const float* __restrict__ Xim, const float* __restrict__ cw1,
    const float* __restrict__ cb1, float* __restrict__ r1, float* __restrict__ i1) {
  int e = blockIdx.x * 256 + threadIdx.x;   // [0, 786432)
  int j = e % 48;
  int row = e / 48;
  int b = row & 3;
  const float* wr = cw1 + b * 2304;
  const float* wi = cw1 + 9216 + b * 2304;
  const float* xr = Xre + (size_t)row * 48;
  const float* xi = Xim + (size_t)row * 48;
  float ar = cb1[b * 48 + j];
  float ai = cb1[192 + b * 48 + j];
#pragma unroll 12
  for (int dd = 0; dd < 48; ++dd) {
    float xrv = xr[dd], xiv = xi[dd];
    float wrv = wr[dd * 48 + j], wiv = wi[dd * 48 + j];
    ar = fmaf(xrv, wrv, ar);
    ar = fmaf(-xiv, wiv, ar);
    ai = fmaf(xrv, wiv, ai);
    ai = fmaf(xiv, wrv, ai);
  }
  r1[e] = fmaxf(ar, 0.f);
  i1[e] = fmaxf(ai, 0.f);
}

// layer 2 + softshrink, writes Z in-place over X
__global__ __launch_bounds__(256) void mix_l2(const float* __restrict__ r1,
    const float* __restrict__ i1, const float* __restrict__ cw2,
    const float* __restrict__ cb2, float* __restrict__ Xre, float* __restrict__ Xim) {
  int e = blockIdx.x * 256 + threadIdx.x;
  int j = e % 48;
  int row = e / 48;
  int b = row & 3;
  const float* wr = cw2 + b * 2304;
  const float* wi = cw2 + 9216 + b * 2304;
  const float* rr = r1 + (size_t)row * 48;
  const float* ri = i1 + (size_t)row * 48;
  float ar = cb2[b * 48 + j];
  float ai = cb2[192 + b * 48 + j];
#pragma unroll 12
  for (int dd = 0; dd < 48; ++dd) {
    float rv = rr[dd], iv = ri[dd];
    float wrv = wr[dd * 48 + j], wiv = wi[dd * 48 + j];
    ar = fmaf(rv, wrv, ar);
    ar = fmaf(-iv, wiv, ar);
    ai = fmaf(rv, wiv, ai);
    ai = fmaf(iv, wrv, ai);
  }
  float zr = (ar > 0.01f) ? ar - 0.01f : ((ar < -0.01f) ? ar + 0.01f : 0.f);
  float zi = (ai > 0.01f) ? ai - 0.01f : ((ai < -0.01f) ? ai + 0.01f : 0.f);
  Xre[e] = zr;
  Xim[e] = zi;
}

// inverse fft2: one block per (Bi,d,c). Inline inverse 4-pt DFT on load,
// IFFT, add residual, write real part.
__global__ __launch_bounds__(256) void fft_inv(const float* __restrict__ Zre,
    const float* __restrict__ Zim, const float* __restrict__ x1, float* __restrict__ out) {
  __shared__ float re[1024];
  __shared__ float im[1024];
  __shared__ float twc[512];
  __shared__ float tws[512];
  int blk = blockIdx.x;
  int c = blk & 3;
  int rest = blk >> 2;
  int d = rest % 48, Bi = rest / 48;
  int tid = threadIdx.x;
  for (int k = tid; k < 512; k += 256) {
    float sv, cv;
    __sincosf(PI_F * (float)k * (1.f / 512.f), &sv, &cv);
    twc[k] = cv; tws[k] = sv;
  }
  for (int k = tid; k < 1024; k += 256) {
    size_t o = ((size_t)(Bi * 1024 + k) * 4) * 48 + d;
    float r0 = Zre[o], r1v = Zre[o + 48], r2 = Zre[o + 96], r3 = Zre[o + 144];
    float i0 = Zim[o], i1v = Zim[o + 48], i2 = Zim[o + 96], i3 = Zim[o + 144];
    float rr, ii;
    if (c == 0)      { rr = r0 + r1v + r2 + r3;  ii = i0 + i1v + i2 + i3; }
    else if (c == 1) { rr = r0 - i1v - r2 + i3;  ii = i0 + r1v - i2 - r3; }
    else if (c == 2) { rr = r0 - r1v + r2 - r3;  ii = i0 - i1v + i2 - i3; }
    else             { rr = r0 + i1v - r2 - i3;  ii = i0 - r1v - i2 + r3; }
    re[k] = rr; im[k] = ii;
  }
  __syncthreads();
  fft1024t(re, im, twc, tws, tid);
  for (int n = tid; n < 1024; n += 256) {
    size_t o = (size_t)(Bi * 1024 + n) * 192 + c * 48 + d;
    out[o] = x1[o] + re[n] * (1.f / 64.f);
  }
}

extern "C" void kernel_launch(void* const* d_in, const int* in_sizes, int n_in,
                              void* d_out, int out_size, void* d_ws, size_t ws_size,
                              hipStream_t stream) {
  const float* x         = (const float*)d_in[0];
  const float* ln1_w     = (const float*)d_in[1];
  const float* ln1_b     = (const float*)d_in[2];
  const float* in_proj_w = (const float*)d_in[3];
  const float* conv_w    = (const float*)d_in[4];
  const float* conv_b    = (const float*)d_in[5];
  const float* x_proj_w  = (const float*)d_in[6];
  const float* dt_proj_w = (const float*)d_in[7];
  const float* dt_proj_b = (const float*)d_in[8];
  const float* A_log     = (const float*)d_in[9];
  const float* Dvec      = (const float*)d_in[10];
  const float* out_proj_w= (const float*)d_in[11];
  const float* ln2_w     = (const float*)d_in[12];
  const float* ln2_b     = (const float*)d_in[13];
  const float* cw1       = (const float*)d_in[14];
  const float* cw2       = (const float*)d_in[15];
  const float* cb1       = (const float*)d_in[16];
  const float* cb2       = (const float*)d_in[17];
  float* out = (float*)d_out;
  float* ws  = (float*)d_ws;

  // workspace layout (floats). Aliases:
  //  duT = Xre+Xim region (dead until fft_fwd), dltT in dlt's slot,
  //  r1/i1 alias dltT/yv (dead after scan / out_proj), x1 = xln.
  float* xz   = ws;                    // 3145728
  float* xc   = xz  + 3145728;         // 1572864
  float* dbc  = xc  + 1572864;         // 573440
  float* dltT = dbc + 573440;          // 1572864
  float* yv   = dltT + 1572864;        // 1572864
  float* xln  = yv  + 1572864;         // 786432
  float* x2   = xln + 786432;          // 786432
  float* Xre  = x2  + 786432;          // 786432
  float* Xim  = Xre + 786432;          // 786432
  float* duT = Xre;                    // 1572864 (spans Xre+Xim)
  float* r1 = dltT;
  float* i1 = yv;
  float* x1 = xln;

  ln_kernel<<<4096, 64, 0, stream>>>(x, ln1_w, ln1_b, xln);
  gemm_tn<<<dim3(12, 64), 256, 0, stream>>>(xln, in_proj_w, nullptr, xz, 4096, 768, 192);
  conv_silu<<<6144, 256, 0, stream>>>(xz, conv_w, conv_b, xc);
  gemm_tn<<<dim3(3, 64), 256, 0, stream>>>(xc, x_proj_w, nullptr, dbc, 4096, 140, 384);
  delta_trans<<<384, 256, 0, stream>>>(dbc, dt_proj_w, dt_proj_b, xc, dltT, duT);
  scan_fused<<<1536, 512, 0, stream>>>(dltT, duT, dbc, A_log, xc, xz, Dvec, yv);
  gemm_tn<<<dim3(3, 64), 256, 0, stream>>>(yv, out_proj_w, x, x1, 4096, 192, 384);
  ln_kernel<<<4096, 64, 0, stream>>>(x1, ln2_w, ln2_b, x2);
  fft_fwd<<<768, 256, 0, stream>>>(x2, Xre, Xim);
  mix_l1<<<3072, 256, 0, stream>>>(Xre, Xim, cw1, cb1, r1, i1);
  mix_l2<<<3072, 256, 0, stream>>>(r1, i1, cw2, cb2, Xre, Xim);
  fft_inv<<<768, 256, 0, stream>>>(Xre, Xim, x1, out);
}

// Round 11
// 389.096 us; speedup vs baseline: 1.1427x; 1.1427x over previous
//
#include <hip/hip_runtime.h>
#include <math.h>

#define PI_F 3.14159265358979323846f

// broadcast lane l's value of v to all lanes (v_readlane -> SGPR)
__device__ __forceinline__ float lane_bcast(float v, int l) {
  return __int_as_float(__builtin_amdgcn_readlane(__float_as_int(v), l));
}

// ---------------- wave reduce ----------------
__device__ __forceinline__ float wave_reduce_sum(float v) {
  v += __shfl_xor(v, 32, 64);
  v += __shfl_xor(v, 16, 64);
  v += __shfl_xor(v, 8, 64);
  v += __shfl_xor(v, 4, 64);
  v += __shfl_xor(v, 2, 64);
  v += __shfl_xor(v, 1, 64);
  return v;
}

// ---------------- LayerNorm: one 64-lane wave per token (C=192) ----------------
__global__ __launch_bounds__(64) void ln_kernel(const float* __restrict__ x,
    const float* __restrict__ w, const float* __restrict__ b, float* __restrict__ o) {
  int row = blockIdx.x;
  int lane = threadIdx.x;
  const float* xr = x + row * 192;
  float v0 = xr[lane], v1 = xr[lane + 64], v2 = xr[lane + 128];
  float s  = wave_reduce_sum(v0 + v1 + v2);
  float s2 = wave_reduce_sum(v0 * v0 + v1 * v1 + v2 * v2);
  float mu  = s * (1.f / 192.f);
  float var = s2 * (1.f / 192.f) - mu * mu;
  float rs  = rsqrtf(var + 1e-5f);
  float* orow = o + row * 192;
  orow[lane]       = (v0 - mu) * rs * w[lane]       + b[lane];
  orow[lane + 64]  = (v1 - mu) * rs * w[lane + 64]  + b[lane + 64];
  orow[lane + 128] = (v2 - mu) * rs * w[lane + 128] + b[lane + 128];
}

// ---------------- pipelined tiled GEMM 64x64: C = A @ W^T (+res) ----------------
__global__ __launch_bounds__(256) void gemm_tn(const float* __restrict__ A,
    const float* __restrict__ W, const float* __restrict__ res, float* __restrict__ C,
    int M, int N, int K) {
  __shared__ float As[2][32][68];   // [buf][k][m]
  __shared__ float Ws[2][32][68];   // [buf][k][n]
  int tid = threadIdx.x;
  int m0 = blockIdx.y * 64, n0 = blockIdx.x * 64;
  int tr = tid >> 4, tc = tid & 15;
  int sm  = tid >> 3;
  int skq = tid & 7;
  float4 aP[2], wP[2];
#pragma unroll
  for (int j = 0; j < 2; ++j) {
    int m = sm + j * 32;
    aP[j] = *(const float4*)(A + (size_t)(m0 + m) * K + skq * 4);
    int n = n0 + m;
    if (n < N) wP[j] = *(const float4*)(W + (size_t)n * K + skq * 4);
    else       wP[j] = make_float4(0.f, 0.f, 0.f, 0.f);
  }
#pragma unroll
  for (int j = 0; j < 2; ++j) {
    int m = sm + j * 32;
    As[0][skq * 4 + 0][m] = aP[j].x;
    As[0][skq * 4 + 1][m] = aP[j].y;
    As[0][skq * 4 + 2][m] = aP[j].z;
    As[0][skq * 4 + 3][m] = aP[j].w;
    Ws[0][skq * 4 + 0][m] = wP[j].x;
    Ws[0][skq * 4 + 1][m] = wP[j].y;
    Ws[0][skq * 4 + 2][m] = wP[j].z;
    Ws[0][skq * 4 + 3][m] = wP[j].w;
  }
  __syncthreads();
  float acc[4][4] = {{0.f}};
  int nk = K >> 5;
  for (int it = 0; it < nk; ++it) {
    int cur = it & 1, nxt = cur ^ 1;
    if (it + 1 < nk) {
      int kk = (it + 1) << 5;
#pragma unroll
      for (int j = 0; j < 2; ++j) {
        int m = sm + j * 32;
        aP[j] = *(const float4*)(A + (size_t)(m0 + m) * K + kk + skq * 4);
        int n = n0 + m;
        if (n < N) wP[j] = *(const float4*)(W + (size_t)n * K + kk + skq * 4);
        else       wP[j] = make_float4(0.f, 0.f, 0.f, 0.f);
      }
    }
#pragma unroll
    for (int k = 0; k < 32; ++k) {
      float4 a4 = *(const float4*)&As[cur][k][tr * 4];
      float4 w4 = *(const float4*)&Ws[cur][k][tc * 4];
      float a[4] = {a4.x, a4.y, a4.z, a4.w};
      float bb[4] = {w4.x, w4.y, w4.z, w4.w};
#pragma unroll
      for (int i = 0; i < 4; ++i)
#pragma unroll
        for (int j = 0; j < 4; ++j)
          acc[i][j] = fmaf(a[i], bb[j], acc[i][j]);
    }
    if (it + 1 < nk) {
#pragma unroll
      for (int j = 0; j < 2; ++j) {
        int m = sm + j * 32;
        As[nxt][skq * 4 + 0][m] = aP[j].x;
        As[nxt][skq * 4 + 1][m] = aP[j].y;
        As[nxt][skq * 4 + 2][m] = aP[j].z;
        As[nxt][skq * 4 + 3][m] = aP[j].w;
        Ws[nxt][skq * 4 + 0][m] = wP[j].x;
        Ws[nxt][skq * 4 + 1][m] = wP[j].y;
        Ws[nxt][skq * 4 + 2][m] = wP[j].z;
        Ws[nxt][skq * 4 + 3][m] = wP[j].w;
      }
      __syncthreads();
    }
  }
#pragma unroll
  for (int i = 0; i < 4; ++i) {
    int m = m0 + tr * 4 + i;
#pragma unroll
    for (int j = 0; j < 4; ++j) {
      int n = n0 + tc * 4 + j;
      if (n < N) {
        float v = acc[i][j];
        if (res) v += res[m * N + n];
        C[m * N + n] = v;
      }
    }
  }
}

// ---------------- pipelined GEMM BM=32 x BN=64 for skinny-N (more blocks) ----
// Same double-buffer structure; 2x4 micro-tile. Grid: (ceil(N/64), M/32).
__global__ __launch_bounds__(256) void gemm_tn32(const float* __restrict__ A,
    const float* __restrict__ W, const float* __restrict__ res, float* __restrict__ C,
    int M, int N, int K) {
  __shared__ float As[2][32][36];   // [buf][k][m(32)]
  __shared__ float Ws[2][32][68];   // [buf][k][n(64)]
  int tid = threadIdx.x;
  int m0 = blockIdx.y * 32, n0 = blockIdx.x * 64;
  int tr = tid >> 4, tc = tid & 15;   // tr: 16 row-groups x2, tc: 16 col-groups x4
  int sm  = tid >> 3;                 // 0..31
  int skq = tid & 7;                  // 0..7
  float4 aP, wP[2];
  aP = *(const float4*)(A + (size_t)(m0 + sm) * K + skq * 4);
#pragma unroll
  for (int j = 0; j < 2; ++j) {
    int n = n0 + sm + j * 32;
    if (n < N) wP[j] = *(const float4*)(W + (size_t)n * K + skq * 4);
    else       wP[j] = make_float4(0.f, 0.f, 0.f, 0.f);
  }
  As[0][skq * 4 + 0][sm] = aP.x;
  As[0][skq * 4 + 1][sm] = aP.y;
  As[0][skq * 4 + 2][sm] = aP.z;
  As[0][skq * 4 + 3][sm] = aP.w;
#pragma unroll
  for (int j = 0; j < 2; ++j) {
    int n = sm + j * 32;
    Ws[0][skq * 4 + 0][n] = wP[j].x;
    Ws[0][skq * 4 + 1][n] = wP[j].y;
    Ws[0][skq * 4 + 2][n] = wP[j].z;
    Ws[0][skq * 4 + 3][n] = wP[j].w;
  }
  __syncthreads();
  float acc[2][4] = {{0.f}};
  int nk = K >> 5;
  for (int it = 0; it < nk; ++it) {
    int cur = it & 1, nxt = cur ^ 1;
    if (it + 1 < nk) {
      int kk = (it + 1) << 5;
      aP = *(const float4*)(A + (size_t)(m0 + sm) * K + kk + skq * 4);
#pragma unroll
      for (int j = 0; j < 2; ++j) {
        int n = n0 + sm + j * 32;
        if (n < N) wP[j] = *(const float4*)(W + (size_t)n * K + kk + skq * 4);
        else       wP[j] = make_float4(0.f, 0.f, 0.f, 0.f);
      }
    }
#pragma unroll
    for (int k = 0; k < 32; ++k) {
      float2 a2 = *(const float2*)&As[cur][k][tr * 2];
      float4 w4 = *(const float4*)&Ws[cur][k][tc * 4];
      float a[2] = {a2.x, a2.y};
      float bb[4] = {w4.x, w4.y, w4.z, w4.w};
#pragma unroll
      for (int i = 0; i < 2; ++i)
#pragma unroll
        for (int j = 0; j < 4; ++j)
          acc[i][j] = fmaf(a[i], bb[j], acc[i][j]);
    }
    if (it + 1 < nk) {
      As[nxt][skq * 4 + 0][sm] = aP.x;
      As[nxt][skq * 4 + 1][sm] = aP.y;
      As[nxt][skq * 4 + 2][sm] = aP.z;
      As[nxt][skq * 4 + 3][sm] = aP.w;
#pragma unroll
      for (int j = 0; j < 2; ++j) {
        int n = sm + j * 32;
        Ws[nxt][skq * 4 + 0][n] = wP[j].x;
        Ws[nxt][skq * 4 + 1][n] = wP[j].y;
        Ws[nxt][skq * 4 + 2][n] = wP[j].z;
        Ws[nxt][skq * 4 + 3][n] = wP[j].w;
      }
      __syncthreads();
    }
  }
#pragma unroll
  for (int i = 0; i < 2; ++i) {
    int m = m0 + tr * 2 + i;
#pragma unroll
    for (int j = 0; j < 4; ++j) {
      int n = n0 + tc * 4 + j;
      if (n < N) {
        float v = acc[i][j];
        if (res) v += res[m * N + n];
        C[m * N + n] = v;
      }
    }
  }
}

// ---------------- causal depthwise conv1d(k=4) + SiLU ----------------
__global__ __launch_bounds__(256) void conv_silu(const float* __restrict__ xz,
    const float* __restrict__ cw, const float* __restrict__ cb, float* __restrict__ xc) {
  int e = blockIdx.x * 256 + threadIdx.x;
  if (e >= 4 * 1024 * 384) return;
  int d = e % 384;
  int t = (e / 384) % 1024;
  int b = e / (384 * 1024);
  const float* base = xz + (size_t)(b * 1024) * 768 + d;
  float acc = cb[d];
#pragma unroll
  for (int j = 0; j < 4; ++j) {
    int tt = t - 3 + j;
    if (tt >= 0) acc += base[(size_t)tt * 768] * cw[d * 4 + j];
  }
  float sg = 1.f / (1.f + __expf(-acc));
  xc[e] = acc * sg;
}

// ---------------- delta + transpose: dltT[b,d,t], duT[b,d,t] = dlt*xc ------
__global__ __launch_bounds__(256) void delta_trans(const float* __restrict__ dbc,
    const float* __restrict__ dtw, const float* __restrict__ dtb,
    const float* __restrict__ xc, float* __restrict__ dltT, float* __restrict__ duT) {
  __shared__ float dts[64][13];
  __shared__ float xt[64][65];
  int blk = blockIdx.x;           // 4 * 16 * 6 = 384
  int b  = blk / 96;
  int rem = blk % 96;
  int tt = rem / 6, dd = rem % 6;
  int t0 = tt * 64, d0 = dd * 64;
  int tid = threadIdx.x;
  for (int i = tid; i < 64 * 12; i += 256) {
    int tl = i / 12, r = i % 12;
    dts[tl][r] = dbc[((size_t)b * 1024 + t0 + tl) * 140 + r];
  }
  {
    int col = tid & 63, rg = tid >> 6;
#pragma unroll
    for (int j = 0; j < 16; ++j) {
      int row = j * 4 + rg;
      xt[row][col] = xc[((size_t)b * 1024 + t0 + row) * 384 + d0 + col];
    }
  }
  __syncthreads();
  int tl = tid & 63, grp = tid >> 6;
#pragma unroll
  for (int j = 0; j < 16; ++j) {
    int dl = grp * 16 + j;
    int d = d0 + dl;
    float s = dtb[d];
#pragma unroll
    for (int r = 0; r < 12; ++r) s += dts[tl][r] * dtw[d * 12 + r];
    float dlt = (s > 20.f) ? s : log1pf(__expf(s));
    size_t ob = ((size_t)b * 384 + d) * 1024 + t0 + tl;
    dltT[ob] = dlt;
    duT[ob]  = dlt * xt[tl][dl];
  }
}

// ---------------- FUSED selective scan: p1+p2+p3+gate, one block per (b,d) ----
// (R8-proven version: 99.6us, VGPR 36 -- do not touch)
__global__ __launch_bounds__(512) void scan_fused(const float* __restrict__ dltT,
    const float* __restrict__ duT, const float* __restrict__ dbc,
    const float* __restrict__ A_log, const float* __restrict__ xc,
    const float* __restrict__ xz, const float* __restrict__ Dvec,
    float* __restrict__ y) {
  __shared__ float tile[8][16][65];
  __shared__ float psP[8][64];
  __shared__ float psS[8][64];
  int bd = blockIdx.x;
  int b = bd / 384, d = bd % 384;
  int tid = threadIdx.x;
  int c = tid >> 6;        // wave index = chunk
  int lane = tid & 63;
  float A = -__expf(A_log[d * 64 + lane]) * 1.44269504f;
  int t0 = c * 128;
  const float* dT = dltT + ((size_t)b * 384 + d) * 1024 + t0;
  const float* uT = duT  + ((size_t)b * 384 + d) * 1024 + t0;
  const float* Bp = dbc + ((size_t)b * 1024 + t0) * 140 + 12 + lane;
  const float* Cp = Bp + 64;
  // ---- phase 1: chunk summary ----
  float Pv = 1.f, Sv = 0.f;
#pragma unroll
  for (int half = 0; half < 2; ++half) {
    float dv64 = dT[half * 64 + lane];
    float du64 = uT[half * 64 + lane];
    for (int tb = 0; tb < 64; tb += 16) {
      float Bv[16];
#pragma unroll
      for (int i = 0; i < 16; ++i)
        Bv[i] = Bp[(size_t)(half * 64 + tb + i) * 140];
#pragma unroll
      for (int i = 0; i < 16; ++i) {
        float sdv = lane_bcast(dv64, tb + i);
        float sdu = lane_bcast(du64, tb + i);
        float a = exp2f(sdv * A);
        Pv *= a;
        Sv = fmaf(Sv, a, sdu * Bv[i]);
      }
    }
  }
  psP[c][lane] = Pv;
  psS[c][lane] = Sv;
  __syncthreads();
  // ---- combine: h_init for this wave's chunk ----
  float h = 0.f;
  for (int k = 0; k < c; ++k)
    h = fmaf(psP[k][lane], h, psS[k][lane]);
  // ---- phase 2: replay + gated write ----
  float ddv = Dvec[d];
  float* yp = y + ((size_t)b * 1024 + t0) * 384 + d;
  const float* xcp = xc + ((size_t)b * 1024 + t0) * 384 + d;
  const float* xzp = xz + ((size_t)b * 1024 + t0) * 768 + 384 + d;
  int tq = lane & 15;
  int q  = lane >> 4;
#pragma unroll
  for (int half = 0; half < 2; ++half) {
    float dv64 = dT[half * 64 + lane];
    float du64 = uT[half * 64 + lane];
    for (int tb = 0; tb < 64; tb += 16) {
      int ts = half * 64 + tb;
      float Bv[16], Cv[16];
#pragma unroll
      for (int i = 0; i < 16; ++i) {
        size_t ro = (size_t)(ts + i) * 140;
        Bv[i] = Bp[ro];
        Cv[i] = Cp[ro];
      }
      float xcv = 0.f, zv = 0.f;
      if (lane < 16) {
        xcv = xcp[(size_t)(ts + lane) * 384];
        zv  = xzp[(size_t)(ts + lane) * 768];
      }
#pragma unroll
      for (int i = 0; i < 16; ++i) {
        float sdv = lane_bcast(dv64, tb + i);
        float sdu = lane_bcast(du64, tb + i);
        float a = exp2f(sdv * A);
        h = fmaf(h, a, sdu * Bv[i]);
        tile[c][i][lane] = h * Cv[i];
      }
      const float* trow = &tile[c][tq][q * 16];
      float s = 0.f;
#pragma unroll
      for (int i = 0; i < 16; ++i) s += trow[i];
      s += __shfl_xor(s, 16, 64);
      s += __shfl_xor(s, 32, 64);
      if (lane < 16) {
        float sg = zv / (1.f + __expf(-zv));
        yp[(size_t)(ts + lane) * 384] = (s + xcv * ddv) * sg;
      }
    }
  }
}

// ---------------- 1024-pt radix-2 FFT in LDS with twiddle table ----------------
__device__ __forceinline__ void fft1024t(float* __restrict__ re,
    float* __restrict__ im, const float* __restrict__ twc,
    const float* __restrict__ tws, int tid) {
  for (int i = tid; i < 1024; i += 256) {
    int r = (int)(__brev((unsigned)i) >> 22);
    if (i < r) {
      float tr = re[i]; re[i] = re[r]; re[r] = tr;
      float ti = im[i]; im[i] = im[r]; im[r] = ti;
    }
  }
  __syncthreads();
  for (int s = 0; s < 10; ++s) {
    int half = 1 << s;
    int shift = 9 - s;
#pragma unroll
    for (int uu = 0; uu < 2; ++uu) {
      int u = tid + uu * 256;
      int j = u & (half - 1);
      int i0 = ((u >> s) << (s + 1)) + j;
      int i1 = i0 + half;
      int idx = j << shift;
      float cw = twc[idx];
      float sw = tws[idx];
      float br = re[i1], bi = im[i1];
      float tr = br * cw - bi * sw;
      float ti = br * sw + bi * cw;
      float ar = re[i0], ai = im[i0];
      re[i1] = ar - tr; im[i1] = ai - ti;
      re[i0] = ar + tr; im[i0] = ai + ti;
    }
    __syncthreads();
  }
}

// forward fft2: one block per (Bi,d,c). Inline 4-pt DFT over c on load.
__global__ __launch_bounds__(256) void fft_fwd(const float* __restrict__ xin,
    float* __restrict__ Xre, float* __restrict__ Xim) {
  __shared__ float re[1024];
  __shared__ float im[1024];
  __shared__ float twc[512];
  __shared__ float tws[512];
  int blk = blockIdx.x;
  int c = blk & 3;
  int rest = blk >> 2;
  int d = rest % 48, Bi = rest / 48;
  int tid = threadIdx.x;
  for (int k = tid; k < 512; k += 256) {
    float sv, cv;
    __sincosf(-PI_F * (float)k * (1.f / 512.f), &sv, &cv);
    twc[k] = cv; tws[k] = sv;
  }
  for (int n = tid; n < 1024; n += 256) {
    const float* p = xin + (size_t)(Bi * 1024 + n) * 192 + d;
    float v0 = p[0], v1 = p[48], v2 = p[96], v3 = p[144];
    float rr, ii;
    if (c == 0)      { rr = v0 + v1 + v2 + v3; ii = 0.f; }
    else if (c == 1) { rr = v0 - v2;           ii = -(v1 - v3); }
    else if (c == 2) { rr = v0 - v1 + v2 - v3; ii = 0.f; }
    else             { rr = v0 - v2;           ii = (v1 - v3); }
    re[n] = rr; im[n] = ii;
  }
  __syncthreads();
  fft1024t(re, im, twc, tws, tid);
  for (int k = tid; k < 1024; k += 256) {
    size_t o = ((size_t)(Bi * 1024 + k) * 4 + c) * 48 + d;
    Xre[o] = re[k] * (1.f / 64.f);
    Xim[o] = im[k] * (1.f / 64.f);
  }
}

// ---------------- EinFFT frequency mix, layer 1 ----------------
__global__ __launch_bounds__(256) void mix_l1(const float* __restrict__ Xre,
    const float* __restrict__ Xim, const float* __restrict__ cw1,
    const float* __restrict__ cb1, float* __restrict__ r1, float* __restrict__ i1) {
  int e = blockIdx.x * 256 + threadIdx.x;   // [0, 786432)
  int j = e % 48;
  int row = e / 48;
  int b = row & 3;
  const float* wr = cw1 + b * 2304;
  const float* wi = cw1 + 9216 + b * 2304;
  const float* xr = Xre + (size_t)row * 48;
  const float* xi = Xim + (size_t)row * 48;
  float ar = cb1[b * 48 + j];
  float ai = cb1[192 + b * 48 + j];
#pragma unroll 12
  for (int dd = 0; dd < 48; ++dd) {
    float xrv = xr[dd], xiv = xi[dd];
    float wrv = wr[dd * 48 + j], wiv = wi[dd * 48 + j];
    ar = fmaf(xrv, wrv, ar);
    ar = fmaf(-xiv, wiv, ar);
    ai = fmaf(xrv, wiv, ai);
    ai = fmaf(xiv, wrv, ai);
  }
  r1[e] = fmaxf(ar, 0.f);
  i1[e] = fmaxf(ai, 0.f);
}

// layer 2 + softshrink, writes Z in-place over X
__global__ __launch_bounds__(256) void mix_l2(const float* __restrict__ r1,
    const float* __restrict__ i1, const float* __restrict__ cw2,
    const float* __restrict__ cb2, float* __restrict__ Xre, float* __restrict__ Xim) {
  int e = blockIdx.x * 256 + threadIdx.x;
  int j = e % 48;
  int row = e / 48;
  int b = row & 3;
  const float* wr = cw2 + b * 2304;
  const float* wi = cw2 + 9216 + b * 2304;
  const float* rr = r1 + (size_t)row * 48;
  const float* ri = i1 + (size_t)row * 48;
  float ar = cb2[b * 48 + j];
  float ai = cb2[192 + b * 48 + j];
#pragma unroll 12
  for (int dd = 0; dd < 48; ++dd) {
    float rv = rr[dd], iv = ri[dd];
    float wrv = wr[dd * 48 + j], wiv = wi[dd * 48 + j];
    ar = fmaf(rv, wrv, ar);
    ar = fmaf(-iv, wiv, ar);
    ai = fmaf(rv, wiv, ai);
    ai = fmaf(iv, wrv, ai);
  }
  float zr = (ar > 0.01f) ? ar - 0.01f : ((ar < -0.01f) ? ar + 0.01f : 0.f);
  float zi = (ai > 0.01f) ? ai - 0.01f : ((ai < -0.01f) ? ai + 0.01f : 0.f);
  Xre[e] = zr;
  Xim[e] = zi;
}

// inverse fft2: one block per (Bi,d,c). Inline inverse 4-pt DFT on load,
// IFFT, add residual, write real part.
__global__ __launch_bounds__(256) void fft_inv(const float* __restrict__ Zre,
    const float* __restrict__ Zim, const float* __restrict__ x1, float* __restrict__ out) {
  __shared__ float re[1024];
  __shared__ float im[1024];
  __shared__ float twc[512];
  __shared__ float tws[512];
  int blk = blockIdx.x;
  int c = blk & 3;
  int rest = blk >> 2;
  int d = rest % 48, Bi = rest / 48;
  int tid = threadIdx.x;
  for (int k = tid; k < 512; k += 256) {
    float sv, cv;
    __sincosf(PI_F * (float)k * (1.f / 512.f), &sv, &cv);
    twc[k] = cv; tws[k] = sv;
  }
  for (int k = tid; k < 1024; k += 256) {
    size_t o = ((size_t)(Bi * 1024 + k) * 4) * 48 + d;
    float r0 = Zre[o], r1v = Zre[o + 48], r2 = Zre[o + 96], r3 = Zre[o + 144];
    float i0 = Zim[o], i1v = Zim[o + 48], i2 = Zim[o + 96], i3 = Zim[o + 144];
    float rr, ii;
    if (c == 0)      { rr = r0 + r1v + r2 + r3;  ii = i0 + i1v + i2 + i3; }
    else if (c == 1) { rr = r0 - i1v - r2 + i3;  ii = i0 + r1v - i2 - r3; }
    else if (c == 2) { rr = r0 - r1v + r2 - r3;  ii = i0 - i1v + i2 - i3; }
    else             { rr = r0 + i1v - r2 - i3;  ii = i0 - r1v - i2 + r3; }
    re[k] = rr; im[k] = ii;
  }
  __syncthreads();
  fft1024t(re, im, twc, tws, tid);
  for (int n = tid; n < 1024; n += 256) {
    size_t o = (size_t)(Bi * 1024 + n) * 192 + c * 48 + d;
    out[o] = x1[o] + re[n] * (1.f / 64.f);
  }
}

extern "C" void kernel_launch(void* const* d_in, const int* in_sizes, int n_in,
                              void* d_out, int out_size, void* d_ws, size_t ws_size,
                              hipStream_t stream) {
  const float* x         = (const float*)d_in[0];
  const float* ln1_w     = (const float*)d_in[1];
  const float* ln1_b     = (const float*)d_in[2];
  const float* in_proj_w = (const float*)d_in[3];
  const float* conv_w    = (const float*)d_in[4];
  const float* conv_b    = (const float*)d_in[5];
  const float* x_proj_w  = (const float*)d_in[6];
  const float* dt_proj_w = (const float*)d_in[7];
  const float* dt_proj_b = (const float*)d_in[8];
  const float* A_log     = (const float*)d_in[9];
  const float* Dvec      = (const float*)d_in[10];
  const float* out_proj_w= (const float*)d_in[11];
  const float* ln2_w     = (const float*)d_in[12];
  const float* ln2_b     = (const float*)d_in[13];
  const float* cw1       = (const float*)d_in[14];
  const float* cw2       = (const float*)d_in[15];
  const float* cb1       = (const float*)d_in[16];
  const float* cb2       = (const float*)d_in[17];
  float* out = (float*)d_out;
  float* ws  = (float*)d_ws;

  // workspace layout (floats). Aliases:
  //  duT = Xre+Xim region (dead until fft_fwd), dltT in dlt's slot,
  //  r1/i1 alias dltT/yv (dead after scan / out_proj), x1 = xln.
  float* xz   = ws;                    // 3145728
  float* xc   = xz  + 3145728;         // 1572864
  float* dbc  = xc  + 1572864;         // 573440
  float* dltT = dbc + 573440;          // 1572864
  float* yv   = dltT + 1572864;        // 1572864
  float* xln  = yv  + 1572864;         // 786432
  float* x2   = xln + 786432;          // 786432
  float* Xre  = x2  + 786432;          // 786432
  float* Xim  = Xre + 786432;          // 786432
  float* duT = Xre;                    // 1572864 (spans Xre+Xim)
  float* r1 = dltT;
  float* i1 = yv;
  float* x1 = xln;

  ln_kernel<<<4096, 64, 0, stream>>>(x, ln1_w, ln1_b, xln);
  gemm_tn<<<dim3(12, 64), 256, 0, stream>>>(xln, in_proj_w, nullptr, xz, 4096, 768, 192);
  conv_silu<<<6144, 256, 0, stream>>>(xz, conv_w, conv_b, xc);
  gemm_tn32<<<dim3(3, 128), 256, 0, stream>>>(xc, x_proj_w, nullptr, dbc, 4096, 140, 384);
  delta_trans<<<384, 256, 0, stream>>>(dbc, dt_proj_w, dt_proj_b, xc, dltT, duT);
  scan_fused<<<1536, 512, 0, stream>>>(dltT, duT, dbc, A_log, xc, xz, Dvec, yv);
  gemm_tn32<<<dim3(3, 128), 256, 0, stream>>>(yv, out_proj_w, x, x1, 4096, 192, 384);
  ln_kernel<<<4096, 64, 0, stream>>>(x1, ln2_w, ln2_b, x2);
  fft_fwd<<<768, 256, 0, stream>>>(x2, Xre, Xim);
  mix_l1<<<3072, 256, 0, stream>>>(Xre, Xim, cw1, cb1, r1, i1);
  mix_l2<<<3072, 256, 0, stream>>>(r1, i1, cw2, cb2, Xre, Xim);
  fft_inv<<<768, 256, 0, stream>>>(Xre, Xim, x1, out);
}

// Round 12
// 385.581 us; speedup vs baseline: 1.1531x; 1.0091x over previous
//
#include <hip/hip_runtime.h>
#include <math.h>

#define PI_F 3.14159265358979323846f

// broadcast lane l's value of v to all lanes (v_readlane -> SGPR)
__device__ __forceinline__ float lane_bcast(float v, int l) {
  return __int_as_float(__builtin_amdgcn_readlane(__float_as_int(v), l));
}

// ---------------- wave reduce ----------------
__device__ __forceinline__ float wave_reduce_sum(float v) {
  v += __shfl_xor(v, 32, 64);
  v += __shfl_xor(v, 16, 64);
  v += __shfl_xor(v, 8, 64);
  v += __shfl_xor(v, 4, 64);
  v += __shfl_xor(v, 2, 64);
  v += __shfl_xor(v, 1, 64);
  return v;
}

// ---------------- LayerNorm: one 64-lane wave per token (C=192) ----------------
__global__ __launch_bounds__(64) void ln_kernel(const float* __restrict__ x,
    const float* __restrict__ w, const float* __restrict__ b, float* __restrict__ o) {
  int row = blockIdx.x;
  int lane = threadIdx.x;
  const float* xr = x + row * 192;
  float v0 = xr[lane], v1 = xr[lane + 64], v2 = xr[lane + 128];
  float s  = wave_reduce_sum(v0 + v1 + v2);
  float s2 = wave_reduce_sum(v0 * v0 + v1 * v1 + v2 * v2);
  float mu  = s * (1.f / 192.f);
  float var = s2 * (1.f / 192.f) - mu * mu;
  float rs  = rsqrtf(var + 1e-5f);
  float* orow = o + row * 192;
  orow[lane]       = (v0 - mu) * rs * w[lane]       + b[lane];
  orow[lane + 64]  = (v1 - mu) * rs * w[lane + 64]  + b[lane + 64];
  orow[lane + 128] = (v2 - mu) * rs * w[lane + 128] + b[lane + 128];
}

// ---------------- pipelined tiled GEMM 64x64: C = A @ W^T (+res) ----------------
__global__ __launch_bounds__(256) void gemm_tn(const float* __restrict__ A,
    const float* __restrict__ W, const float* __restrict__ res, float* __restrict__ C,
    int M, int N, int K) {
  __shared__ float As[2][32][68];   // [buf][k][m]
  __shared__ float Ws[2][32][68];   // [buf][k][n]
  int tid = threadIdx.x;
  int m0 = blockIdx.y * 64, n0 = blockIdx.x * 64;
  int tr = tid >> 4, tc = tid & 15;
  int sm  = tid >> 3;
  int skq = tid & 7;
  float4 aP[2], wP[2];
#pragma unroll
  for (int j = 0; j < 2; ++j) {
    int m = sm + j * 32;
    aP[j] = *(const float4*)(A + (size_t)(m0 + m) * K + skq * 4);
    int n = n0 + m;
    if (n < N) wP[j] = *(const float4*)(W + (size_t)n * K + skq * 4);
    else       wP[j] = make_float4(0.f, 0.f, 0.f, 0.f);
  }
#pragma unroll
  for (int j = 0; j < 2; ++j) {
    int m = sm + j * 32;
    As[0][skq * 4 + 0][m] = aP[j].x;
    As[0][skq * 4 + 1][m] = aP[j].y;
    As[0][skq * 4 + 2][m] = aP[j].z;
    As[0][skq * 4 + 3][m] = aP[j].w;
    Ws[0][skq * 4 + 0][m] = wP[j].x;
    Ws[0][skq * 4 + 1][m] = wP[j].y;
    Ws[0][skq * 4 + 2][m] = wP[j].z;
    Ws[0][skq * 4 + 3][m] = wP[j].w;
  }
  __syncthreads();
  float acc[4][4] = {{0.f}};
  int nk = K >> 5;
  for (int it = 0; it < nk; ++it) {
    int cur = it & 1, nxt = cur ^ 1;
    if (it + 1 < nk) {
      int kk = (it + 1) << 5;
#pragma unroll
      for (int j = 0; j < 2; ++j) {
        int m = sm + j * 32;
        aP[j] = *(const float4*)(A + (size_t)(m0 + m) * K + kk + skq * 4);
        int n = n0 + m;
        if (n < N) wP[j] = *(const float4*)(W + (size_t)n * K + kk + skq * 4);
        else       wP[j] = make_float4(0.f, 0.f, 0.f, 0.f);
      }
    }
#pragma unroll
    for (int k = 0; k < 32; ++k) {
      float4 a4 = *(const float4*)&As[cur][k][tr * 4];
      float4 w4 = *(const float4*)&Ws[cur][k][tc * 4];
      float a[4] = {a4.x, a4.y, a4.z, a4.w};
      float bb[4] = {w4.x, w4.y, w4.z, w4.w};
#pragma unroll
      for (int i = 0; i < 4; ++i)
#pragma unroll
        for (int j = 0; j < 4; ++j)
          acc[i][j] = fmaf(a[i], bb[j], acc[i][j]);
    }
    if (it + 1 < nk) {
#pragma unroll
      for (int j = 0; j < 2; ++j) {
        int m = sm + j * 32;
        As[nxt][skq * 4 + 0][m] = aP[j].x;
        As[nxt][skq * 4 + 1][m] = aP[j].y;
        As[nxt][skq * 4 + 2][m] = aP[j].z;
        As[nxt][skq * 4 + 3][m] = aP[j].w;
        Ws[nxt][skq * 4 + 0][m] = wP[j].x;
        Ws[nxt][skq * 4 + 1][m] = wP[j].y;
        Ws[nxt][skq * 4 + 2][m] = wP[j].z;
        Ws[nxt][skq * 4 + 3][m] = wP[j].w;
      }
      __syncthreads();
    }
  }
#pragma unroll
  for (int i = 0; i < 4; ++i) {
    int m = m0 + tr * 4 + i;
#pragma unroll
    for (int j = 0; j < 4; ++j) {
      int n = n0 + tc * 4 + j;
      if (n < N) {
        float v = acc[i][j];
        if (res) v += res[m * N + n];
        C[m * N + n] = v;
      }
    }
  }
}

// ---------------- pipelined GEMM BM=32 x BN=64 for skinny-N ----------------
__global__ __launch_bounds__(256) void gemm_tn32(const float* __restrict__ A,
    const float* __restrict__ W, const float* __restrict__ res, float* __restrict__ C,
    int M, int N, int K) {
  __shared__ float As[2][32][36];   // [buf][k][m(32)]
  __shared__ float Ws[2][32][68];   // [buf][k][n(64)]
  int tid = threadIdx.x;
  int m0 = blockIdx.y * 32, n0 = blockIdx.x * 64;
  int tr = tid >> 4, tc = tid & 15;
  int sm  = tid >> 3;
  int skq = tid & 7;
  float4 aP, wP[2];
  aP = *(const float4*)(A + (size_t)(m0 + sm) * K + skq * 4);
#pragma unroll
  for (int j = 0; j < 2; ++j) {
    int n = n0 + sm + j * 32;
    if (n < N) wP[j] = *(const float4*)(W + (size_t)n * K + skq * 4);
    else       wP[j] = make_float4(0.f, 0.f, 0.f, 0.f);
  }
  As[0][skq * 4 + 0][sm] = aP.x;
  As[0][skq * 4 + 1][sm] = aP.y;
  As[0][skq * 4 + 2][sm] = aP.z;
  As[0][skq * 4 + 3][sm] = aP.w;
#pragma unroll
  for (int j = 0; j < 2; ++j) {
    int n = sm + j * 32;
    Ws[0][skq * 4 + 0][n] = wP[j].x;
    Ws[0][skq * 4 + 1][n] = wP[j].y;
    Ws[0][skq * 4 + 2][n] = wP[j].z;
    Ws[0][skq * 4 + 3][n] = wP[j].w;
  }
  __syncthreads();
  float acc[2][4] = {{0.f}};
  int nk = K >> 5;
  for (int it = 0; it < nk; ++it) {
    int cur = it & 1, nxt = cur ^ 1;
    if (it + 1 < nk) {
      int kk = (it + 1) << 5;
      aP = *(const float4*)(A + (size_t)(m0 + sm) * K + kk + skq * 4);
#pragma unroll
      for (int j = 0; j < 2; ++j) {
        int n = n0 + sm + j * 32;
        if (n < N) wP[j] = *(const float4*)(W + (size_t)n * K + kk + skq * 4);
        else       wP[j] = make_float4(0.f, 0.f, 0.f, 0.f);
      }
    }
#pragma unroll
    for (int k = 0; k < 32; ++k) {
      float2 a2 = *(const float2*)&As[cur][k][tr * 2];
      float4 w4 = *(const float4*)&Ws[cur][k][tc * 4];
      float a[2] = {a2.x, a2.y};
      float bb[4] = {w4.x, w4.y, w4.z, w4.w};
#pragma unroll
      for (int i = 0; i < 2; ++i)
#pragma unroll
        for (int j = 0; j < 4; ++j)
          acc[i][j] = fmaf(a[i], bb[j], acc[i][j]);
    }
    if (it + 1 < nk) {
      As[nxt][skq * 4 + 0][sm] = aP.x;
      As[nxt][skq * 4 + 1][sm] = aP.y;
      As[nxt][skq * 4 + 2][sm] = aP.z;
      As[nxt][skq * 4 + 3][sm] = aP.w;
#pragma unroll
      for (int j = 0; j < 2; ++j) {
        int n = sm + j * 32;
        Ws[nxt][skq * 4 + 0][n] = wP[j].x;
        Ws[nxt][skq * 4 + 1][n] = wP[j].y;
        Ws[nxt][skq * 4 + 2][n] = wP[j].z;
        Ws[nxt][skq * 4 + 3][n] = wP[j].w;
      }
      __syncthreads();
    }
  }
#pragma unroll
  for (int i = 0; i < 2; ++i) {
    int m = m0 + tr * 2 + i;
#pragma unroll
    for (int j = 0; j < 4; ++j) {
      int n = n0 + tc * 4 + j;
      if (n < N) {
        float v = acc[i][j];
        if (res) v += res[m * N + n];
        C[m * N + n] = v;
      }
    }
  }
}

// ---------------- gemm_tn32 with TRANSPOSED A: AT[(bb*KT + k)*1024 + t] ----
// m = bb*1024 + t (rows of a 32-row tile share bb). KT = K. A-staging reads
// contiguous t-runs (coalesced) and lands directly in [k][m] LDS order.
__global__ __launch_bounds__(256) void gemm_at32(const float* __restrict__ AT,
    const float* __restrict__ W, const float* __restrict__ res, float* __restrict__ C,
    int M, int N, int K) {
  __shared__ float As[2][32][36];   // [buf][k][m(32)]
  __shared__ float Ws[2][32][68];   // [buf][k][n(64)]
  int tid = threadIdx.x;
  int m0 = blockIdx.y * 32, n0 = blockIdx.x * 64;
  int bb = m0 >> 10;
  int t0 = m0 & 1023;
  const float* Ab = AT + ((size_t)bb * K) * 1024 + t0;
  int tr = tid >> 4, tc = tid & 15;
  int sm  = tid >> 3;   // k row for A-staging / n row for W-staging
  int skq = tid & 7;
  float4 aP, wP[2];
  aP = *(const float4*)(Ab + (size_t)sm * 1024 + skq * 4);
#pragma unroll
  for (int j = 0; j < 2; ++j) {
    int n = n0 + sm + j * 32;
    if (n < N) wP[j] = *(const float4*)(W + (size_t)n * K + skq * 4);
    else       wP[j] = make_float4(0.f, 0.f, 0.f, 0.f);
  }
  *(float4*)&As[0][sm][skq * 4] = aP;
#pragma unroll
  for (int j = 0; j < 2; ++j) {
    int n = sm + j * 32;
    Ws[0][skq * 4 + 0][n] = wP[j].x;
    Ws[0][skq * 4 + 1][n] = wP[j].y;
    Ws[0][skq * 4 + 2][n] = wP[j].z;
    Ws[0][skq * 4 + 3][n] = wP[j].w;
  }
  __syncthreads();
  float acc[2][4] = {{0.f}};
  int nk = K >> 5;
  for (int it = 0; it < nk; ++it) {
    int cur = it & 1, nxt = cur ^ 1;
    if (it + 1 < nk) {
      int kk = (it + 1) << 5;
      aP = *(const float4*)(Ab + (size_t)(kk + sm) * 1024 + skq * 4);
#pragma unroll
      for (int j = 0; j < 2; ++j) {
        int n = n0 + sm + j * 32;
        if (n < N) wP[j] = *(const float4*)(W + (size_t)n * K + kk + skq * 4);
        else       wP[j] = make_float4(0.f, 0.f, 0.f, 0.f);
      }
    }
#pragma unroll
    for (int k = 0; k < 32; ++k) {
      float2 a2 = *(const float2*)&As[cur][k][tr * 2];
      float4 w4 = *(const float4*)&Ws[cur][k][tc * 4];
      float a[2] = {a2.x, a2.y};
      float bb4[4] = {w4.x, w4.y, w4.z, w4.w};
#pragma unroll
      for (int i = 0; i < 2; ++i)
#pragma unroll
        for (int j = 0; j < 4; ++j)
          acc[i][j] = fmaf(a[i], bb4[j], acc[i][j]);
    }
    if (it + 1 < nk) {
      *(float4*)&As[nxt][sm][skq * 4] = aP;
#pragma unroll
      for (int j = 0; j < 2; ++j) {
        int n = sm + j * 32;
        Ws[nxt][skq * 4 + 0][n] = wP[j].x;
        Ws[nxt][skq * 4 + 1][n] = wP[j].y;
        Ws[nxt][skq * 4 + 2][n] = wP[j].z;
        Ws[nxt][skq * 4 + 3][n] = wP[j].w;
      }
      __syncthreads();
    }
  }
#pragma unroll
  for (int i = 0; i < 2; ++i) {
    int m = m0 + tr * 2 + i;
#pragma unroll
    for (int j = 0; j < 4; ++j) {
      int n = n0 + tc * 4 + j;
      if (n < N) {
        float v = acc[i][j];
        if (res) v += res[m * N + n];
        C[m * N + n] = v;
      }
    }
  }
}

// ---------------- causal depthwise conv1d(k=4) + SiLU ----------------
__global__ __launch_bounds__(256) void conv_silu(const float* __restrict__ xz,
    const float* __restrict__ cw, const float* __restrict__ cb, float* __restrict__ xc) {
  int e = blockIdx.x * 256 + threadIdx.x;
  if (e >= 4 * 1024 * 384) return;
  int d = e % 384;
  int t = (e / 384) % 1024;
  int b = e / (384 * 1024);
  const float* base = xz + (size_t)(b * 1024) * 768 + d;
  float acc = cb[d];
#pragma unroll
  for (int j = 0; j < 4; ++j) {
    int tt = t - 3 + j;
    if (tt >= 0) acc += base[(size_t)tt * 768] * cw[d * 4 + j];
  }
  float sg = 1.f / (1.f + __expf(-acc));
  xc[e] = acc * sg;
}

// ---------------- delta + transpose: dltT[b,d,t], duT[b,d,t] = dlt*xc ------
__global__ __launch_bounds__(256) void delta_trans(const float* __restrict__ dbc,
    const float* __restrict__ dtw, const float* __restrict__ dtb,
    const float* __restrict__ xc, float* __restrict__ dltT, float* __restrict__ duT) {
  __shared__ float dts[64][13];
  __shared__ float xt[64][65];
  int blk = blockIdx.x;           // 4 * 16 * 6 = 384
  int b  = blk / 96;
  int rem = blk % 96;
  int tt = rem / 6, dd = rem % 6;
  int t0 = tt * 64, d0 = dd * 64;
  int tid = threadIdx.x;
  for (int i = tid; i < 64 * 12; i += 256) {
    int tl = i / 12, r = i % 12;
    dts[tl][r] = dbc[((size_t)b * 1024 + t0 + tl) * 140 + r];
  }
  {
    int col = tid & 63, rg = tid >> 6;
#pragma unroll
    for (int j = 0; j < 16; ++j) {
      int row = j * 4 + rg;
      xt[row][col] = xc[((size_t)b * 1024 + t0 + row) * 384 + d0 + col];
    }
  }
  __syncthreads();
  int tl = tid & 63, grp = tid >> 6;
#pragma unroll
  for (int j = 0; j < 16; ++j) {
    int dl = grp * 16 + j;
    int d = d0 + dl;
    float s = dtb[d];
#pragma unroll
    for (int r = 0; r < 12; ++r) s += dts[tl][r] * dtw[d * 12 + r];
    float dlt = (s > 20.f) ? s : log1pf(__expf(s));
    size_t ob = ((size_t)b * 384 + d) * 1024 + t0 + tl;
    dltT[ob] = dlt;
    duT[ob]  = dlt * xt[tl][dl];
  }
}

// ---------------- FUSED selective scan: p1+p2+p3+gate, one block per (b,d) ----
// Writes y TRANSPOSED: yT[(b*384+d)*1024 + t] -- the 16 reduced lanes land on
// 16 consecutive floats (one 64B transaction vs 16 scattered sectors).
__global__ __launch_bounds__(512) void scan_fused(const float* __restrict__ dltT,
    const float* __restrict__ duT, const float* __restrict__ dbc,
    const float* __restrict__ A_log, const float* __restrict__ xc,
    const float* __restrict__ xz, const float* __restrict__ Dvec,
    float* __restrict__ yT) {
  __shared__ float tile[8][16][65];
  __shared__ float psP[8][64];
  __shared__ float psS[8][64];
  int bd = blockIdx.x;
  int b = bd / 384, d = bd % 384;
  int tid = threadIdx.x;
  int c = tid >> 6;        // wave index = chunk
  int lane = tid & 63;
  float A = -__expf(A_log[d * 64 + lane]) * 1.44269504f;
  int t0 = c * 128;
  const float* dT = dltT + ((size_t)b * 384 + d) * 1024 + t0;
  const float* uT = duT  + ((size_t)b * 384 + d) * 1024 + t0;
  const float* Bp = dbc + ((size_t)b * 1024 + t0) * 140 + 12 + lane;
  const float* Cp = Bp + 64;
  // ---- phase 1: chunk summary ----
  float Pv = 1.f, Sv = 0.f;
#pragma unroll
  for (int half = 0; half < 2; ++half) {
    float dv64 = dT[half * 64 + lane];
    float du64 = uT[half * 64 + lane];
    for (int tb = 0; tb < 64; tb += 16) {
      float Bv[16];
#pragma unroll
      for (int i = 0; i < 16; ++i)
        Bv[i] = Bp[(size_t)(half * 64 + tb + i) * 140];
#pragma unroll
      for (int i = 0; i < 16; ++i) {
        float sdv = lane_bcast(dv64, tb + i);
        float sdu = lane_bcast(du64, tb + i);
        float a = exp2f(sdv * A);
        Pv *= a;
        Sv = fmaf(Sv, a, sdu * Bv[i]);
      }
    }
  }
  psP[c][lane] = Pv;
  psS[c][lane] = Sv;
  __syncthreads();
  // ---- combine: h_init for this wave's chunk ----
  float h = 0.f;
  for (int k = 0; k < c; ++k)
    h = fmaf(psP[k][lane], h, psS[k][lane]);
  // ---- phase 2: replay + gated coalesced write ----
  float ddv = Dvec[d];
  float* yp = yT + ((size_t)b * 384 + d) * 1024 + t0;
  const float* xcp = xc + ((size_t)b * 1024 + t0) * 384 + d;
  const float* xzp = xz + ((size_t)b * 1024 + t0) * 768 + 384 + d;
  int tq = lane & 15;
  int q  = lane >> 4;
#pragma unroll
  for (int half = 0; half < 2; ++half) {
    float dv64 = dT[half * 64 + lane];
    float du64 = uT[half * 64 + lane];
    for (int tb = 0; tb < 64; tb += 16) {
      int ts = half * 64 + tb;
      float Bv[16], Cv[16];
#pragma unroll
      for (int i = 0; i < 16; ++i) {
        size_t ro = (size_t)(ts + i) * 140;
        Bv[i] = Bp[ro];
        Cv[i] = Cp[ro];
      }
      float xcv = 0.f, zv = 0.f;
      if (lane < 16) {
        xcv = xcp[(size_t)(ts + lane) * 384];
        zv  = xzp[(size_t)(ts + lane) * 768];
      }
#pragma unroll
      for (int i = 0; i < 16; ++i) {
        float sdv = lane_bcast(dv64, tb + i);
        float sdu = lane_bcast(du64, tb + i);
        float a = exp2f(sdv * A);
        h = fmaf(h, a, sdu * Bv[i]);
        tile[c][i][lane] = h * Cv[i];
      }
      const float* trow = &tile[c][tq][q * 16];
      float s = 0.f;
#pragma unroll
      for (int i = 0; i < 16; ++i) s += trow[i];
      s += __shfl_xor(s, 16, 64);
      s += __shfl_xor(s, 32, 64);
      if (lane < 16) {
        float sg = zv / (1.f + __expf(-zv));
        yp[ts + lane] = (s + xcv * ddv) * sg;
      }
    }
  }
}

// ---------------- 1024-pt radix-2 FFT in LDS with twiddle table ----------------
__device__ __forceinline__ void fft1024t(float* __restrict__ re,
    float* __restrict__ im, const float* __restrict__ twc,
    const float* __restrict__ tws, int tid) {
  for (int i = tid; i < 1024; i += 256) {
    int r = (int)(__brev((unsigned)i) >> 22);
    if (i < r) {
      float tr = re[i]; re[i] = re[r]; re[r] = tr;
      float ti = im[i]; im[i] = im[r]; im[r] = ti;
    }
  }
  __syncthreads();
  for (int s = 0; s < 10; ++s) {
    int half = 1 << s;
    int shift = 9 - s;
#pragma unroll
    for (int uu = 0; uu < 2; ++uu) {
      int u = tid + uu * 256;
      int j = u & (half - 1);
      int i0 = ((u >> s) << (s + 1)) + j;
      int i1 = i0 + half;
      int idx = j << shift;
      float cw = twc[idx];
      float sw = tws[idx];
      float br = re[i1], bi = im[i1];
      float tr = br * cw - bi * sw;
      float ti = br * sw + bi * cw;
      float ar = re[i0], ai = im[i0];
      re[i1] = ar - tr; im[i1] = ai - ti;
      re[i0] = ar + tr; im[i0] = ai + ti;
    }
    __syncthreads();
  }
}

// forward fft2: one block per (Bi,d,c). Inline 4-pt DFT over c on load.
__global__ __launch_bounds__(256) void fft_fwd(const float* __restrict__ xin,
    float* __restrict__ Xre, float* __restrict__ Xim) {
  __shared__ float re[1024];
  __shared__ float im[1024];
  __shared__ float twc[512];
  __shared__ float tws[512];
  int blk = blockIdx.x;
  int c = blk & 3;
  int rest = blk >> 2;
  int d = rest % 48, Bi = rest / 48;
  int tid = threadIdx.x;
  for (int k = tid; k < 512; k += 256) {
    float sv, cv;
    __sincosf(-PI_F * (float)k * (1.f / 512.f), &sv, &cv);
    twc[k] = cv; tws[k] = sv;
  }
  for (int n = tid; n < 1024; n += 256) {
    const float* p = xin + (size_t)(Bi * 1024 + n) * 192 + d;
    float v0 = p[0], v1 = p[48], v2 = p[96], v3 = p[144];
    float rr, ii;
    if (c == 0)      { rr = v0 + v1 + v2 + v3; ii = 0.f; }
    else if (c == 1) { rr = v0 - v2;           ii = -(v1 - v3); }
    else if (c == 2) { rr = v0 - v1 + v2 - v3; ii = 0.f; }
    else             { rr = v0 - v2;           ii = (v1 - v3); }
    re[n] = rr; im[n] = ii;
  }
  __syncthreads();
  fft1024t(re, im, twc, tws, tid);
  for (int k = tid; k < 1024; k += 256) {
    size_t o = ((size_t)(Bi * 1024 + k) * 4 + c) * 48 + d;
    Xre[o] = re[k] * (1.f / 64.f);
    Xim[o] = im[k] * (1.f / 64.f);
  }
}

// ---------------- EinFFT frequency mix, layer 1 ----------------
__global__ __launch_bounds__(256) void mix_l1(const float* __restrict__ Xre,
    const float* __restrict__ Xim, const float* __restrict__ cw1,
    const float* __restrict__ cb1, float* __restrict__ r1, float* __restrict__ i1) {
  int e = blockIdx.x * 256 + threadIdx.x;   // [0, 786432)
  int j = e % 48;
  int row = e / 48;
  int b = row & 3;
  const float* wr = cw1 + b * 2304;
  const float* wi = cw1 + 9216 + b * 2304;
  const float* xr = Xre + (size_t)row * 48;
  const float* xi = Xim + (size_t)row * 48;
  float ar = cb1[b * 48 + j];
  float ai = cb1[192 + b * 48 + j];
#pragma unroll 12
  for (int dd = 0; dd < 48; ++dd) {
    float xrv = xr[dd], xiv = xi[dd];
    float wrv = wr[dd * 48 + j], wiv = wi[dd * 48 + j];
    ar = fmaf(xrv, wrv, ar);
    ar = fmaf(-xiv, wiv, ar);
    ai = fmaf(xrv, wiv, ai);
    ai = fmaf(xiv, wrv, ai);
  }
  r1[e] = fmaxf(ar, 0.f);
  i1[e] = fmaxf(ai, 0.f);
}

// layer 2 + softshrink, writes Z in-place over X
__global__ __launch_bounds__(256) void mix_l2(const float* __restrict__ r1,
    const float* __restrict__ i1, const float* __restrict__ cw2,
    const float* __restrict__ cb2, float* __restrict__ Xre, float* __restrict__ Xim) {
  int e = blockIdx.x * 256 + threadIdx.x;
  int j = e % 48;
  int row = e / 48;
  int b = row & 3;
  const float* wr = cw2 + b * 2304;
  const float* wi = cw2 + 9216 + b * 2304;
  const float* rr = r1 + (size_t)row * 48;
  const float* ri = i1 + (size_t)row * 48;
  float ar = cb2[b * 48 + j];
  float ai = cb2[192 + b * 48 + j];
#pragma unroll 12
  for (int dd = 0; dd < 48; ++dd) {
    float rv = rr[dd], iv = ri[dd];
    float wrv = wr[dd * 48 + j], wiv = wi[dd * 48 + j];
    ar = fmaf(rv, wrv, ar);
    ar = fmaf(-iv, wiv, ar);
    ai = fmaf(rv, wiv, ai);
    ai = fmaf(iv, wrv, ai);
  }
  float zr = (ar > 0.01f) ? ar - 0.01f : ((ar < -0.01f) ? ar + 0.01f : 0.f);
  float zi = (ai > 0.01f) ? ai - 0.01f : ((ai < -0.01f) ? ai + 0.01f : 0.f);
  Xre[e] = zr;
  Xim[e] = zi;
}

// inverse fft2: one block per (Bi,d,c). Inline inverse 4-pt DFT on load,
// IFFT, add residual, write real part.
__global__ __launch_bounds__(256) void fft_inv(const float* __restrict__ Zre,
    const float* __restrict__ Zim, const float* __restrict__ x1, float* __restrict__ out) {
  __shared__ float re[1024];
  __shared__ float im[1024];
  __shared__ float twc[512];
  __shared__ float tws[512];
  int blk = blockIdx.x;
  int c = blk & 3;
  int rest = blk >> 2;
  int d = rest % 48, Bi = rest / 48;
  int tid = threadIdx.x;
  for (int k = tid; k < 512; k += 256) {
    float sv, cv;
    __sincosf(PI_F * (float)k * (1.f / 512.f), &sv, &cv);
    twc[k] = cv; tws[k] = sv;
  }
  for (int k = tid; k < 1024; k += 256) {
    size_t o = ((size_t)(Bi * 1024 + k) * 4) * 48 + d;
    float r0 = Zre[o], r1v = Zre[o + 48], r2 = Zre[o + 96], r3 = Zre[o + 144];
    float i0 = Zim[o], i1v = Zim[o + 48], i2 = Zim[o + 96], i3 = Zim[o + 144];
    float rr, ii;
    if (c == 0)      { rr = r0 + r1v + r2 + r3;  ii = i0 + i1v + i2 + i3; }
    else if (c == 1) { rr = r0 - i1v - r2 + i3;  ii = i0 + r1v - i2 - r3; }
    else if (c == 2) { rr = r0 - r1v + r2 - r3;  ii = i0 - i1v + i2 - i3; }
    else             { rr = r0 + i1v - r2 - i3;  ii = i0 - r1v - i2 + r3; }
    re[k] = rr; im[k] = ii;
  }
  __syncthreads();
  fft1024t(re, im, twc, tws, tid);
  for (int n = tid; n < 1024; n += 256) {
    size_t o = (size_t)(Bi * 1024 + n) * 192 + c * 48 + d;
    out[o] = x1[o] + re[n] * (1.f / 64.f);
  }
}

extern "C" void kernel_launch(void* const* d_in, const int* in_sizes, int n_in,
                              void* d_out, int out_size, void* d_ws, size_t ws_size,
                              hipStream_t stream) {
  const float* x         = (const float*)d_in[0];
  const float* ln1_w     = (const float*)d_in[1];
  const float* ln1_b     = (const float*)d_in[2];
  const float* in_proj_w = (const float*)d_in[3];
  const float* conv_w    = (const float*)d_in[4];
  const float* conv_b    = (const float*)d_in[5];
  const float* x_proj_w  = (const float*)d_in[6];
  const float* dt_proj_w = (const float*)d_in[7];
  const float* dt_proj_b = (const float*)d_in[8];
  const float* A_log     = (const float*)d_in[9];
  const float* Dvec      = (const float*)d_in[10];
  const float* out_proj_w= (const float*)d_in[11];
  const float* ln2_w     = (const float*)d_in[12];
  const float* ln2_b     = (const float*)d_in[13];
  const float* cw1       = (const float*)d_in[14];
  const float* cw2       = (const float*)d_in[15];
  const float* cb1       = (const float*)d_in[16];
  const float* cb2       = (const float*)d_in[17];
  float* out = (float*)d_out;
  float* ws  = (float*)d_ws;

  // workspace layout (floats). Aliases:
  //  duT = Xre+Xim region (dead until fft_fwd), dltT in dlt's slot,
  //  r1/i1 alias dltT/yvT (dead after scan / out_proj), x1 = xln.
  float* xz   = ws;                    // 3145728
  float* xc   = xz  + 3145728;         // 1572864
  float* dbc  = xc  + 1572864;         // 573440
  float* dltT = dbc + 573440;          // 1572864
  float* yvT  = dltT + 1572864;        // 1572864 (TRANSPOSED y: [b][d][t])
  float* xln  = yvT + 1572864;         // 786432
  float* x2   = xln + 786432;          // 786432
  float* Xre  = x2  + 786432;          // 786432
  float* Xim  = Xre + 786432;          // 786432
  float* duT = Xre;                    // 1572864 (spans Xre+Xim)
  float* r1 = dltT;
  float* i1 = yvT;
  float* x1 = xln;

  ln_kernel<<<4096, 64, 0, stream>>>(x, ln1_w, ln1_b, xln);
  gemm_tn<<<dim3(12, 64), 256, 0, stream>>>(xln, in_proj_w, nullptr, xz, 4096, 768, 192);
  conv_silu<<<6144, 256, 0, stream>>>(xz, conv_w, conv_b, xc);
  gemm_tn32<<<dim3(3, 128), 256, 0, stream>>>(xc, x_proj_w, nullptr, dbc, 4096, 140, 384);
  delta_trans<<<384, 256, 0, stream>>>(dbc, dt_proj_w, dt_proj_b, xc, dltT, duT);
  scan_fused<<<1536, 512, 0, stream>>>(dltT, duT, dbc, A_log, xc, xz, Dvec, yvT);
  gemm_at32<<<dim3(3, 128), 256, 0, stream>>>(yvT, out_proj_w, x, x1, 4096, 192, 384);
  ln_kernel<<<4096, 64, 0, stream>>>(x1, ln2_w, ln2_b, x2);
  fft_fwd<<<768, 256, 0, stream>>>(x2, Xre, Xim);
  mix_l1<<<3072, 256, 0, stream>>>(Xre, Xim, cw1, cb1, r1, i1);
  mix_l2<<<3072, 256, 0, stream>>>(r1, i1, cw2, cb2, Xre, Xim);
  fft_inv<<<768, 256, 0, stream>>>(Xre, Xim, x1, out);
}